// Round 13
// baseline (228.307 us; speedup 1.0000x reference)
//
#include <hip/hip_runtime.h>

// ============================================================================
// ROUND 25 = R24 base (measured best, 202.69us) + combine FOLDED INTO o_gemm.
//  - o_gemm now reg-stages its A operand directly from opart (fp32, both
//    split-K halves) + lpart: load 8 float4/thread/tile, normalize
//    (o1+o2)*inv in regs (same add order + same f2bf as combine ->
//    bit-identical), ds_write into the exact tiled LDS layout the MFMA loop
//    already reads (group*2048 + tid*8 == off64(row,k) intra-tile).
//    inv[16] precomputed once (thread's row is fixed). Fully-unrolled
//    16-tile loop, 2 named reg sets (static parity), NBUF=3, per-phase
//    {issue A-loads+B-gld for i+2} -> WAITVM(10) -> ds_write(i+1) ->
//    lgkm(0) -> sbar (T14 async-split; tile i+1's loads fly a full phase).
//    Removes combine's 16.25MB read + 4MB write + ao buffer + 1 launch.
//  - prep (R24 LDS-transpose), qkv_gemm (R15 best), attn_split (R24
//    setprio) unchanged.
// ============================================================================

typedef __attribute__((ext_vector_type(8))) short short8;
typedef __attribute__((ext_vector_type(4))) short short4v;
typedef __attribute__((ext_vector_type(4))) float f32x4;
typedef __attribute__((ext_vector_type(4))) int int4v;

#define SCL2E 0.18033688011112042592f /* (1/8) * log2(e) */

__device__ __forceinline__ short f2bf(float f) {
  unsigned u = __float_as_uint(f);
  u += 0x7fffu + ((u >> 16) & 1u);
  return (short)(u >> 16);
}
__device__ __forceinline__ int cvt_pk_bf16(float a, float b) {
  int r;
  asm("v_cvt_pk_bf16_f32 %0, %1, %2" : "=v"(r) : "v"(a), "v"(b));
  return r;
}
__device__ __forceinline__ void gld_lds16(const void* gp, void* lp) {
  __builtin_amdgcn_global_load_lds(
      (const __attribute__((address_space(1))) unsigned int*)gp,
      (__attribute__((address_space(3))) unsigned int*)lp, 16, 0, 0);
}
__device__ __forceinline__ void sbar() {
  __builtin_amdgcn_sched_barrier(0);
  __builtin_amdgcn_s_barrier();
  __builtin_amdgcn_sched_barrier(0);
}
#define WAITVM(N) asm volatile("s_waitcnt vmcnt(" #N ")" ::: "memory")
#define WAITLGKM0 asm volatile("s_waitcnt lgkmcnt(0)" ::: "memory")

__device__ __forceinline__ void pipesync() {
  asm volatile("s_waitcnt vmcnt(0) lgkmcnt(0)" ::: "memory");
  __builtin_amdgcn_sched_barrier(0);
  __builtin_amdgcn_s_barrier();
  __builtin_amdgcn_sched_barrier(0);
}
__device__ __forceinline__ short4v cvt4(float4 v) {
  short4v o;
  o[0] = f2bf(v.x); o[1] = f2bf(v.y); o[2] = f2bf(v.z); o[3] = f2bf(v.w);
  return o;
}

// ---------------------------------------------------------------------------
// prep (R24): mask bit-pack (all 2048 blocks) + LDS-transpose fp32->bf16
// tiled conversion (blocks 0..1279, one 64x128 chunk each).
// ---------------------------------------------------------------------------
__global__ __launch_bounds__(256) void prep(
    const unsigned char* __restrict__ mask, unsigned long long* __restrict__ pm,
    const float* __restrict__ Wq, const float* __restrict__ Wkv,
    const float* __restrict__ Wo, const float* __restrict__ x,
    const float* __restrict__ ctx, short* __restrict__ wqb,
    short* __restrict__ wkvb, short* __restrict__ wob,
    short* __restrict__ xb, short* __restrict__ ctxb) {
  __shared__ __align__(16) short lds[64][136];
  const int row = blockIdx.x;
  const int wave = threadIdx.x >> 6, lane = threadIdx.x & 63;
  const unsigned char p8 = mask[lane * 4 + 1];
  const int p32 = ((const int*)mask)[lane * 2 + 1];
  const int shift =
      (__ballot(p8 != 0) != 0ull) ? 0 : ((__ballot(p32 != 0) != 0ull) ? 2 : 3);
  const size_t mbase = ((size_t)row * 2048) << shift;
#pragma unroll
  for (int j = 0; j < 8; j++) {
    const int c = wave * 512 + j * 64 + lane;
    const unsigned long long bits = __ballot(mask[mbase + ((size_t)c << shift)] != 0);
    if (lane == 0) pm[(size_t)row * 32 + wave * 8 + j] = bits;
  }

  const int bid = blockIdx.x;
  if (bid >= 1280) return;  // uniform per-block branch
  const float* src;
  short* dst;
  int cb;
  bool t64 = false;
  if (bid < 256) {
    src = x; dst = xb; cb = bid;
  } else if (bid < 768) {
    src = ctx; dst = ctxb; cb = bid - 256;
  } else if (bid < 1024) {
    src = Wkv; dst = wkvb; cb = bid - 768;
  } else if (bid < 1152) {
    src = Wq; dst = wqb; cb = bid - 1024;
  } else {
    src = Wo; dst = wob; cb = bid - 1152; t64 = true;
  }
  const int R0 = (cb >> 3) * 64, C0 = (cb & 7) * 128;
  const int t = threadIdx.x;
#pragma unroll
  for (int p = 0; p < 8; p++) {
    const int r = R0 + p * 8 + (t >> 5), c = C0 + (t & 31) * 4;
    const float4 v = *(const float4*)(src + (size_t)r * 1024 + c);
    *(short4v*)&lds[p * 8 + (t >> 5)][(t & 31) * 4] = cvt4(v);
  }
  __syncthreads();
  const int rt = t64 ? (R0 >> 6) : (R0 >> 7);
  const int f0 = t64 ? 0 : ((R0 >> 6) & 1) * 4;
  const int fl = t >> 6, q = (t >> 4) & 3, r15 = t & 15;
  const int lrow = fl * 16 + r15;
#pragma unroll
  for (int kc_l = 0; kc_l < 4; kc_l++) {
    const int kc = (C0 >> 5) + kc_l;
    const size_t base = t64 ? ((size_t)((rt * 32 + kc) * 4)) * 512
                            : ((size_t)((rt * 32 + kc) * 8 + f0)) * 512;
    const short8 vv = *(const short8*)&lds[lrow][kc_l * 32 + q * 8];
    *(short8*)(dst + base + t * 8) = vv;
  }
}

// ---------------------------------------------------------------------------
// qkv_gemm (R15 exact, measured best): 128x128 tile, BK=32, NBUF=3 (48KB),
// counted vmcnt(4), one barrier per phase, XCD-chunked swizzle, 3 blocks/CU.
// ---------------------------------------------------------------------------
__global__ __launch_bounds__(256, 3)
void qkv_gemm(const short* __restrict__ xb, const short* __restrict__ ctxb,
              const short* __restrict__ wqb, const short* __restrict__ wkvb,
              const float* __restrict__ bias, short* __restrict__ qws,
              short* __restrict__ kws, short* __restrict__ vtws) {
  __shared__ __align__(16) short ldsA[3][4096];
  __shared__ __align__(16) short ldsB[3][4096];
  const int tid = threadIdx.x;
  const int wave = tid >> 6, lane = tid & 63;
  const int l15 = lane & 15, lg = lane >> 4;
  const int bx0 = blockIdx.x;
  const int bx = (bx0 & 7) * 80 + (bx0 >> 3);
  const bool isKV = bx < 512;
  const int rt = isKV ? (bx >> 4) : ((bx - 512) >> 3);
  const int ct = isKV ? (bx & 15) : ((bx - 512) & 7);
  const short* Amat = isKV ? ctxb : xb;
  const short* Bw = isKV ? wkvb : wqb;
  const int wr = wave >> 1, wc = wave & 1;

  f32x4 acc[4][4];
#pragma unroll
  for (int i = 0; i < 4; i++)
#pragma unroll
    for (int j = 0; j < 4; j++) acc[i][j] = (f32x4){0.f, 0.f, 0.f, 0.f};

  const short* ga0 = Amat + (size_t)rt * 131072 + wave * 512 + lane * 8;
  const short* ga1 = ga0 + 2048;
  const short* gb0 = Bw + (size_t)ct * 131072 + wave * 512 + lane * 8;
  const short* gb1 = gb0 + 2048;

  auto stage = [&](int kk, int buf) {
    const size_t koff = (size_t)kk * 4096;
    short* dA = &ldsA[buf][0];
    short* dB = &ldsB[buf][0];
    gld_lds16(ga0 + koff, dA + wave * 512);
    gld_lds16(ga1 + koff, dA + (wave + 4) * 512);
    gld_lds16(gb0 + koff, dB + wave * 512);
    gld_lds16(gb1 + koff, dB + (wave + 4) * 512);
  };
  auto compute = [&](int buf) {
    const short* sA = &ldsA[buf][0];
    const short* sB = &ldsB[buf][0];
    short8 af[4], bfr[4];
#pragma unroll
    for (int t = 0; t < 4; t++)
      af[t] = *(const short8*)&sA[((wr * 4 + t) * 64 + lane) * 8];
#pragma unroll
    for (int t = 0; t < 4; t++)
      bfr[t] = *(const short8*)&sB[((wc * 4 + t) * 64 + lane) * 8];
#pragma unroll
    for (int i = 0; i < 4; i++)
#pragma unroll
      for (int j = 0; j < 4; j++)
        acc[i][j] =
            __builtin_amdgcn_mfma_f32_16x16x32_bf16(af[i], bfr[j], acc[i][j], 0, 0, 0);
  };

  stage(0, 0);
  stage(1, 1);
  int cur = 0, nxt = 2;
  for (int i = 0; i < 30; ++i) {
    WAITVM(4);
    sbar();
    stage(i + 2, nxt);
    compute(cur);
    cur = (cur == 2) ? 0 : cur + 1;
    nxt = (nxt == 2) ? 0 : nxt + 1;
  }
  WAITVM(4);
  sbar();
  compute(cur);
  cur = (cur == 2) ? 0 : cur + 1;
  WAITVM(0);
  sbar();
  compute(cur);

#pragma unroll
  for (int i = 0; i < 4; i++)
#pragma unroll
    for (int j = 0; j < 4; j++)
#pragma unroll
      for (int r = 0; r < 4; r++) {
        const int gr = rt * 128 + wr * 64 + i * 16 + lg * 4 + r;
        const int gc = ct * 128 + wc * 64 + j * 16 + l15;
        float v = acc[i][j][r];
        if (isKV) {
          v += bias[gc];
          const int b = gr >> 11, m = gr & 2047;
          const int kv = gc >> 10, hh = (gc >> 6) & 15, d = gc & 63;
          if (kv == 0)
            kws[((((size_t)b * 16 + hh) * 2048 + m) << 6) + d] = f2bf(v);
          else {
            // permuted V^T column so attn's in-register P-frag order matches
            const int mp = (m & ~31) | (((m >> 2) & 3) << 3) |
                           (((m >> 4) & 1) << 2) | (m & 3);
            vtws[(((size_t)b * 16 + hh) * 64 + d) * 2048 + mp] = f2bf(v);
          }
        } else {
          const int b = gr >> 10, n = gr & 1023, hh = gc >> 6, d = gc & 63;
          qws[((((size_t)b * 16 + hh) * 1024 + n) << 6) + d] = f2bf(v * SCL2E);
        }
      }
}

// ---------------------------------------------------------------------------
// attn_split (R24: R17 structure + T5 setprio): swapped QK^T in-register P;
// NBUF=2 K/V full-phase counted-vmcnt cover; all 8 mask uint4 preloaded;
// fully unrolled. 512 blocks x 512 threads, split-K x2. LDS 64KB.
// ---------------------------------------------------------------------------
__global__ __launch_bounds__(512, 4)
void attn_split(const short* __restrict__ Qg, const short* __restrict__ Kg,
                const short* __restrict__ Vtg,
                const unsigned int* __restrict__ pm,
                float* __restrict__ opart, float* __restrict__ lpart) {
  __shared__ __align__(16) short ldsK[2][8192];
  __shared__ __align__(16) short ldsV[2][8192];
  const int tid = threadIdx.x;
  const int w = tid >> 6, lane = tid & 63;
  const int l15 = lane & 15, lg = lane >> 4;
  const int bx = blockIdx.x;
  const int bhid = bx & 31, qt = (bx >> 5) & 7, half = bx >> 8;
  const int b = bhid >> 4, h = bhid & 15;
  const int n0 = qt * 128, m_base = half * 1024;
  const size_t bh = (size_t)b * 16 + h;
  const short* Qb = Qg + (bh * 1024 + n0) * 64;
  const short* Kb = Kg + (bh << 17);
  const short* Vb = Vtg + (bh << 17);
  const unsigned int* pmw =
      pm + ((size_t)(b * 1024 + n0 + w * 16 + l15) << 6) + (m_base >> 5);

  uint4 mku[8];
#pragma unroll
  for (int c = 0; c < 8; c++) mku[c] = *(const uint4*)(pmw + c * 4);

  auto stageKV = [&](int c, int buf) {
    const int m0 = m_base + c * 128;
    short* dK = &ldsK[buf][0];
    short* dV = &ldsV[buf][0];
#pragma unroll
    for (int ii = 0; ii < 2; ii++) {
      const int f = w * 2 + ii;
      const int t = f >> 1, ks = f & 1;
      gld_lds16(Kb + (size_t)(m0 + t * 16 + l15) * 64 + ks * 32 + lg * 8,
                dK + f * 512);
      const int vt = f >> 2, vk = f & 3;
      gld_lds16(Vb + (size_t)(vt * 16 + l15) * 2048 + (m0 + vk * 32 + lg * 8),
                dV + f * 512);
    }
  };

#pragma unroll
  for (int ii = 0; ii < 2; ii++)
    gld_lds16(Qb + (size_t)(w * 16 + l15) * 64 + ii * 32 + lg * 8,
              &ldsV[1][(w * 2 + ii) * 512]);
  stageKV(0, 0);
  pipesync();
  short8 qf[2];
#pragma unroll
  for (int ks = 0; ks < 2; ks++)
    qf[ks] = *(const short8*)&ldsV[1][((w * 2 + ks) * 64 + lane) * 8];
  WAITLGKM0;
  sbar();

  short8 onesf;
#pragma unroll
  for (int i = 0; i < 8; i++) onesf[i] = (short)0x3F80;  // bf16 1.0

  f32x4 o[4], lacc;
#pragma unroll
  for (int ct = 0; ct < 4; ct++) o[ct] = (f32x4){0.f, 0.f, 0.f, 0.f};
  lacc = (f32x4){0.f, 0.f, 0.f, 0.f};
  const int sb = lg * 4;

  auto computeC = [&](uint4 mk, int buf) {
    const short* sK = &ldsK[buf][0];
    const short* sV = &ldsV[buf][0];
    int4v pw4[4];
#pragma unroll
    for (int h2 = 0; h2 < 2; h2++) {
      f32x4 s[4];
#pragma unroll
      for (int t2 = 0; t2 < 4; t2++) s[t2] = (f32x4){0.f, 0.f, 0.f, 0.f};
      __builtin_amdgcn_s_setprio(1);
#pragma unroll
      for (int t2 = 0; t2 < 4; t2++) {
        const int t = h2 * 4 + t2;
#pragma unroll
        for (int ks = 0; ks < 2; ks++) {
          const short8 kf = *(const short8*)&sK[((t * 2 + ks) * 64 + lane) * 8];
          s[t2] = __builtin_amdgcn_mfma_f32_16x16x32_bf16(kf, qf[ks], s[t2], 0, 0, 0);
        }
      }
      __builtin_amdgcn_s_setprio(0);
#pragma unroll
      for (int t2 = 0; t2 < 4; t2++) {
        const int t = h2 * 4 + t2;
        const unsigned int mw = ((t >> 1) == 0) ? mk.x
                              : ((t >> 1) == 1) ? mk.y
                              : ((t >> 1) == 2) ? mk.z : mk.w;
        float p[4];
#pragma unroll
        for (int r = 0; r < 4; r++) {
          const bool att = (mw >> (((t & 1) << 4) + sb + r)) & 1;
          p[r] = exp2f(att ? s[t2][r] : -1e30f);
        }
        pw4[t >> 1][(t & 1) * 2] = cvt_pk_bf16(p[0], p[1]);
        pw4[t >> 1][(t & 1) * 2 + 1] = cvt_pk_bf16(p[2], p[3]);
      }
    }
    __builtin_amdgcn_s_setprio(1);
#pragma unroll
    for (int ks2 = 0; ks2 < 4; ks2++) {
      const short8 pf = __builtin_bit_cast(short8, pw4[ks2]);
#pragma unroll
      for (int ct = 0; ct < 4; ct++) {
        const short8 vf = *(const short8*)&sV[((ct * 4 + ks2) * 64 + lane) * 8];
        o[ct] = __builtin_amdgcn_mfma_f32_16x16x32_bf16(pf, vf, o[ct], 0, 0, 0);
      }
      lacc = __builtin_amdgcn_mfma_f32_16x16x32_bf16(pf, onesf, lacc, 0, 0, 0);
    }
    __builtin_amdgcn_s_setprio(0);
  };

#pragma unroll
  for (int c = 0; c < 8; c++) {
    if (c + 1 < 8) {
      stageKV(c + 1, (c + 1) & 1);
      WAITVM(4);
    } else {
      WAITVM(0);
    }
    sbar();
    computeC(mku[c], c & 1);
    sbar();
  }

#pragma unroll
  for (int ct = 0; ct < 4; ct++)
#pragma unroll
    for (int r = 0; r < 4; r++) {
      const int n = n0 + w * 16 + lg * 4 + r;
      opart[((size_t)half << 21) + (((size_t)b * 1024 + n) << 10) + h * 64 +
            ct * 16 + l15] = o[ct][r];
    }
  if (l15 == 0) {
#pragma unroll
    for (int r = 0; r < 4; r++) {
      const int n = n0 + w * 16 + lg * 4 + r;
      lpart[((size_t)half << 15) + bh * 1024 + n] = lacc[r];
    }
  }
}

// ---------------------------------------------------------------------------
// o_gemm (R25, combine fused): 64x64 tiles, BK=64, 512 blocks, NBUF=3.
// A = normalized AO computed on the fly: per tile, 8 float4 loads from
// opart (both halves), (o1+o2)*inv[t] in regs (inv precomputed; thread's
// row fixed), cvt4 -> ds_write into the SAME tiled LDS layout as before.
// B = wob via gld_lds (unchanged). Fully unrolled, 2 named reg sets.
// Per iter: sbar -> issue {A-loads,B-gld}(i+2) -> compute(i) ->
// WAITVM(10) [tile i+1 retired] -> ds_write A(i+1) -> lgkm(0).
// ---------------------------------------------------------------------------
__global__ __launch_bounds__(256, 3)
void o_gemm(const float* __restrict__ opart, const float* __restrict__ lpart,
            const short* __restrict__ wobT, float* __restrict__ Of) {
  __shared__ __align__(16) short ldsA[3][4096];
  __shared__ __align__(16) short ldsB[3][4096];
  const int tid = threadIdx.x;
  const int w = tid >> 6, lane = tid & 63;
  const int l15 = lane & 15, lg = lane >> 4;
  const int bx0 = blockIdx.x;
  const int bx = (bx0 & 7) * 64 + (bx0 >> 3);
  const int rt = bx >> 4, ct = bx & 15;

  // --- A-staging thread geometry: row fixed for the whole kernel ---
  const int arow = rt * 64 + (tid >> 6) * 16 + (tid & 15);
  const int kq8 = ((tid >> 4) & 3) * 8;
  const int ab = arow >> 10, an = arow & 1023;
  const float* srcA = opart + ((size_t)arow << 10);

  float inv[16];
#pragma unroll
  for (int h = 0; h < 16; h++) {
    const float l1 = lpart[(size_t)(ab * 16 + h) * 1024 + an];
    const float l2 = lpart[(1u << 15) + (size_t)(ab * 16 + h) * 1024 + an];
    inv[h] = 1.f / fmaxf(l1 + l2, 1e-30f);
  }

  f32x4 acc[4];
#pragma unroll
  for (int j = 0; j < 4; j++) acc[j] = (f32x4){0.f, 0.f, 0.f, 0.f};

  const short* gb = wobT + (size_t)ct * 65536 + w * 512 + lane * 8;

  float4 rg[2][8];  // two named reg sets (static index after full unroll)
  auto loadA = [&](float4* r, int t) {
    const float* p = srcA + t * 64 + kq8;
    r[0] = *(const float4*)(p);
    r[1] = *(const float4*)(p + 4);
    r[2] = *(const float4*)(p + 32);
    r[3] = *(const float4*)(p + 36);
    const float* p2 = p + (1u << 21);
    r[4] = *(const float4*)(p2);
    r[5] = *(const float4*)(p2 + 4);
    r[6] = *(const float4*)(p2 + 32);
    r[7] = *(const float4*)(p2 + 36);
  };
  auto stageB = [&](int t, int buf) {
    const size_t koff = (size_t)t * 4096;
    gld_lds16(gb + koff, &ldsB[buf][0] + w * 512);
    gld_lds16(gb + koff + 2048, &ldsB[buf][0] + 2048 + w * 512);
  };
  auto writeA = [&](const float4* r, int t, int buf) {
    const float iv = inv[t];
    const float4 q0 = (r[0] + r[4]) * iv;
    const float4 q1 = (r[1] + r[5]) * iv;
    const float4 q2 = (r[2] + r[6]) * iv;
    const float4 q3 = (r[3] + r[7]) * iv;
    *(short4v*)&ldsA[buf][tid * 8] = cvt4(q0);
    *(short4v*)&ldsA[buf][tid * 8 + 4] = cvt4(q1);
    *(short4v*)&ldsA[buf][2048 + tid * 8] = cvt4(q2);
    *(short4v*)&ldsA[buf][2048 + tid * 8 + 4] = cvt4(q3);
  };
  auto compute = [&](int buf) {
    const short* sA = &ldsA[buf][0];
    const short* sB = &ldsB[buf][0];
    const short8 af0 = *(const short8*)&sA[(w * 64 + lane) * 8];
    const short8 af1 = *(const short8*)&sA[2048 + (w * 64 + lane) * 8];
#pragma unroll
    for (int j = 0; j < 4; j++) {
      const short8 bf0 = *(const short8*)&sB[(j * 64 + lane) * 8];
      const short8 bf1 = *(const short8*)&sB[2048 + (j * 64 + lane) * 8];
      acc[j] = __builtin_amdgcn_mfma_f32_16x16x32_bf16(af0, bf0, acc[j], 0, 0, 0);
      acc[j] = __builtin_amdgcn_mfma_f32_16x16x32_bf16(af1, bf1, acc[j], 0, 0, 0);
    }
  };

  // Prologue: tiles 0 and 1 issued; tile 0 written to LDS.
  loadA(rg[0], 0);
  stageB(0, 0);
  loadA(rg[1], 1);
  stageB(1, 1);
  WAITVM(10);          // tile 0's 10 ops retired (tile 1's outstanding)
  writeA(rg[0], 0, 0);
  WAITLGKM0;

  // Main: 16 tiles, fully unrolled (all reg/buf indices compile-time).
#pragma unroll
  for (int i = 0; i < 16; i++) {
    sbar();  // buf i%3 ready (A written + B gld'd by all waves)
    if (i + 2 < 16) {
      loadA(rg[i & 1], i + 2);  // reg set of tile i (already ds_written)
      stageB(i + 2, (i + 2) % 3);
    }
    compute(i % 3);
    if (i + 1 < 16) {
      if (i + 2 < 16) {
        WAITVM(10);  // tile i+1's 10 ops retired; tile i+2's in flight
      } else {
        WAITVM(0);   // last outstanding tile (15)
      }
      writeA(rg[(i + 1) & 1], i + 1, (i + 1) % 3);
    }
    WAITLGKM0;  // my ds_writes drained before next barrier
  }

#pragma unroll
  for (int j = 0; j < 4; j++)
#pragma unroll
    for (int r = 0; r < 4; r++) {
      const int gr = rt * 64 + w * 16 + lg * 4 + r;
      const int gc = ct * 64 + j * 16 + l15;
      Of[(size_t)gr * 1024 + gc] = acc[j][r];
    }
}

extern "C" void kernel_launch(void* const* d_in, const int* in_sizes, int n_in,
                              void* d_out, int out_size, void* d_ws, size_t ws_size,
                              hipStream_t stream) {
  const float* x   = (const float*)d_in[0];   // fp32 (2,1024,1024)
  const float* ctx = (const float*)d_in[1];   // fp32 (2,2048,1024)
  const unsigned char* mask = (const unsigned char*)d_in[2];  // (2,1024,2048)
  const float* Wq  = (const float*)d_in[3];
  const float* Wkv = (const float*)d_in[4];
  const float* bkv = (const float*)d_in[5];
  const float* Wo  = (const float*)d_in[6];
  float* out = (float*)d_out;                 // FP32 (2,1024,1024)

  char* wsb = (char*)d_ws;
  short* qws  = (short*)(wsb);                        // bf16 Q*scl  4MB @0
  short* kws  = (short*)(wsb + (4u << 20));           // bf16 K      8MB @4M
  short* vtws = (short*)(wsb + (12u << 20));          // bf16 V^T    8MB @12M
  short* wqb  = (short*)(wsb + (20u << 20));          // bf16 Wq(T)  2MB @20M
  short* wkvb = (short*)(wsb + (22u << 20));          // bf16 Wkv(T) 4MB @22M
  short* wob  = (short*)(wsb + (26u << 20));          // bf16 Wo(T)  2MB @26M
  unsigned long long* pmws = (unsigned long long*)(wsb + (28u << 20));  // .5MB
  float* opart = (float*)(wsb + (29u << 20));         // fp32 2x8MB  16MB @29M
  float* lpart = (float*)(wsb + (45u << 20));         // fp32 .25MB  @45M
  short* xb   = (short*)(wsb + (29u << 20));          // bf16 x(T)   4MB @29M (dead before attn)
  short* ctxb = (short*)(wsb + (33u << 20));          // bf16 ctx(T) 8MB @33M (dead before attn)

  prep<<<2048, 256, 0, stream>>>(mask, pmws, Wq, Wkv, Wo, x, ctx,
                                 wqb, wkvb, wob, xb, ctxb);
  qkv_gemm<<<640, 256, 0, stream>>>(xb, ctxb, wqb, wkvb, bkv, qws, kws, vtws);
  attn_split<<<512, 512, 0, stream>>>(qws, kws, vtws, (const unsigned int*)pmws,
                                      opart, lpart);
  o_gemm<<<512, 256, 0, stream>>>(opart, lpart, wob, out);
}

// Round 14
// 202.109 us; speedup vs baseline: 1.1296x; 1.1296x over previous
//
#include <hip/hip_runtime.h>

// ============================================================================
// ROUND 26 = R24 EXACT RESTORE (measured best, 202.69us).
// R25's combine->o_gemm fusion regressed 25.6us (reg-staged gather A-path +
// uncoalesced lpart loads replaced 2-instr gld_lds staging; same failure
// class as R23). Both fusion attempts lost more inside the fused kernel
// than the removed traffic/launch saved. Restoring the best-measured
// pipeline: prep (LDS-transpose), qkv_gemm (R15 NBUF=3 + XCD swizzle),
// attn_split (R17 structure + T5 setprio), combine (output-linear),
// o_gemm (R17 BK=64 NBUF=3).
// ============================================================================

typedef __attribute__((ext_vector_type(8))) short short8;
typedef __attribute__((ext_vector_type(4))) short short4v;
typedef __attribute__((ext_vector_type(4))) float f32x4;
typedef __attribute__((ext_vector_type(4))) int int4v;

#define SCL2E 0.18033688011112042592f /* (1/8) * log2(e) */

__device__ __forceinline__ short f2bf(float f) {
  unsigned u = __float_as_uint(f);
  u += 0x7fffu + ((u >> 16) & 1u);
  return (short)(u >> 16);
}
__device__ __forceinline__ int cvt_pk_bf16(float a, float b) {
  int r;
  asm("v_cvt_pk_bf16_f32 %0, %1, %2" : "=v"(r) : "v"(a), "v"(b));
  return r;
}
__device__ __forceinline__ void gld_lds16(const void* gp, void* lp) {
  __builtin_amdgcn_global_load_lds(
      (const __attribute__((address_space(1))) unsigned int*)gp,
      (__attribute__((address_space(3))) unsigned int*)lp, 16, 0, 0);
}
__device__ __forceinline__ void sbar() {
  __builtin_amdgcn_sched_barrier(0);
  __builtin_amdgcn_s_barrier();
  __builtin_amdgcn_sched_barrier(0);
}
#define WAITVM(N) asm volatile("s_waitcnt vmcnt(" #N ")" ::: "memory")

__device__ __forceinline__ void pipesync() {
  asm volatile("s_waitcnt vmcnt(0) lgkmcnt(0)" ::: "memory");
  __builtin_amdgcn_sched_barrier(0);
  __builtin_amdgcn_s_barrier();
  __builtin_amdgcn_sched_barrier(0);
}
__device__ __forceinline__ short4v cvt4(float4 v) {
  short4v o;
  o[0] = f2bf(v.x); o[1] = f2bf(v.y); o[2] = f2bf(v.z); o[3] = f2bf(v.w);
  return o;
}
// 64-row tiled layout (combine epilogue only).
__device__ __forceinline__ size_t off64(int row, int k) {
  return ((size_t)(((row >> 6) * 32 + (k >> 5)) * 4 + ((row >> 4) & 3)) << 9) +
         (((((k >> 3) & 3) * 16 + (row & 15)) << 3) + (k & 7));
}

// ---------------------------------------------------------------------------
// prep (R24): mask bit-pack (all 2048 blocks) + LDS-transpose fp32->bf16
// tiled conversion (blocks 0..1279, one 64x128 chunk each).
// ---------------------------------------------------------------------------
__global__ __launch_bounds__(256) void prep(
    const unsigned char* __restrict__ mask, unsigned long long* __restrict__ pm,
    const float* __restrict__ Wq, const float* __restrict__ Wkv,
    const float* __restrict__ Wo, const float* __restrict__ x,
    const float* __restrict__ ctx, short* __restrict__ wqb,
    short* __restrict__ wkvb, short* __restrict__ wob,
    short* __restrict__ xb, short* __restrict__ ctxb) {
  __shared__ __align__(16) short lds[64][136];
  const int row = blockIdx.x;
  const int wave = threadIdx.x >> 6, lane = threadIdx.x & 63;
  const unsigned char p8 = mask[lane * 4 + 1];
  const int p32 = ((const int*)mask)[lane * 2 + 1];
  const int shift =
      (__ballot(p8 != 0) != 0ull) ? 0 : ((__ballot(p32 != 0) != 0ull) ? 2 : 3);
  const size_t mbase = ((size_t)row * 2048) << shift;
#pragma unroll
  for (int j = 0; j < 8; j++) {
    const int c = wave * 512 + j * 64 + lane;
    const unsigned long long bits = __ballot(mask[mbase + ((size_t)c << shift)] != 0);
    if (lane == 0) pm[(size_t)row * 32 + wave * 8 + j] = bits;
  }

  const int bid = blockIdx.x;
  if (bid >= 1280) return;  // uniform per-block branch
  const float* src;
  short* dst;
  int cb;
  bool t64 = false;
  if (bid < 256) {
    src = x; dst = xb; cb = bid;
  } else if (bid < 768) {
    src = ctx; dst = ctxb; cb = bid - 256;
  } else if (bid < 1024) {
    src = Wkv; dst = wkvb; cb = bid - 768;
  } else if (bid < 1152) {
    src = Wq; dst = wqb; cb = bid - 1024;
  } else {
    src = Wo; dst = wob; cb = bid - 1152; t64 = true;
  }
  const int R0 = (cb >> 3) * 64, C0 = (cb & 7) * 128;
  const int t = threadIdx.x;
#pragma unroll
  for (int p = 0; p < 8; p++) {
    const int r = R0 + p * 8 + (t >> 5), c = C0 + (t & 31) * 4;
    const float4 v = *(const float4*)(src + (size_t)r * 1024 + c);
    *(short4v*)&lds[p * 8 + (t >> 5)][(t & 31) * 4] = cvt4(v);
  }
  __syncthreads();
  const int rt = t64 ? (R0 >> 6) : (R0 >> 7);
  const int f0 = t64 ? 0 : ((R0 >> 6) & 1) * 4;
  const int fl = t >> 6, q = (t >> 4) & 3, r15 = t & 15;
  const int lrow = fl * 16 + r15;
#pragma unroll
  for (int kc_l = 0; kc_l < 4; kc_l++) {
    const int kc = (C0 >> 5) + kc_l;
    const size_t base = t64 ? ((size_t)((rt * 32 + kc) * 4)) * 512
                            : ((size_t)((rt * 32 + kc) * 8 + f0)) * 512;
    const short8 vv = *(const short8*)&lds[lrow][kc_l * 32 + q * 8];
    *(short8*)(dst + base + t * 8) = vv;
  }
}

// ---------------------------------------------------------------------------
// qkv_gemm (R15 exact, measured best): 128x128 tile, BK=32, NBUF=3 (48KB),
// counted vmcnt(4), one barrier per phase, XCD-chunked swizzle, 3 blocks/CU.
// ---------------------------------------------------------------------------
__global__ __launch_bounds__(256, 3)
void qkv_gemm(const short* __restrict__ xb, const short* __restrict__ ctxb,
              const short* __restrict__ wqb, const short* __restrict__ wkvb,
              const float* __restrict__ bias, short* __restrict__ qws,
              short* __restrict__ kws, short* __restrict__ vtws) {
  __shared__ __align__(16) short ldsA[3][4096];
  __shared__ __align__(16) short ldsB[3][4096];
  const int tid = threadIdx.x;
  const int wave = tid >> 6, lane = tid & 63;
  const int l15 = lane & 15, lg = lane >> 4;
  const int bx0 = blockIdx.x;
  const int bx = (bx0 & 7) * 80 + (bx0 >> 3);
  const bool isKV = bx < 512;
  const int rt = isKV ? (bx >> 4) : ((bx - 512) >> 3);
  const int ct = isKV ? (bx & 15) : ((bx - 512) & 7);
  const short* Amat = isKV ? ctxb : xb;
  const short* Bw = isKV ? wkvb : wqb;
  const int wr = wave >> 1, wc = wave & 1;

  f32x4 acc[4][4];
#pragma unroll
  for (int i = 0; i < 4; i++)
#pragma unroll
    for (int j = 0; j < 4; j++) acc[i][j] = (f32x4){0.f, 0.f, 0.f, 0.f};

  const short* ga0 = Amat + (size_t)rt * 131072 + wave * 512 + lane * 8;
  const short* ga1 = ga0 + 2048;
  const short* gb0 = Bw + (size_t)ct * 131072 + wave * 512 + lane * 8;
  const short* gb1 = gb0 + 2048;

  auto stage = [&](int kk, int buf) {
    const size_t koff = (size_t)kk * 4096;
    short* dA = &ldsA[buf][0];
    short* dB = &ldsB[buf][0];
    gld_lds16(ga0 + koff, dA + wave * 512);
    gld_lds16(ga1 + koff, dA + (wave + 4) * 512);
    gld_lds16(gb0 + koff, dB + wave * 512);
    gld_lds16(gb1 + koff, dB + (wave + 4) * 512);
  };
  auto compute = [&](int buf) {
    const short* sA = &ldsA[buf][0];
    const short* sB = &ldsB[buf][0];
    short8 af[4], bfr[4];
#pragma unroll
    for (int t = 0; t < 4; t++)
      af[t] = *(const short8*)&sA[((wr * 4 + t) * 64 + lane) * 8];
#pragma unroll
    for (int t = 0; t < 4; t++)
      bfr[t] = *(const short8*)&sB[((wc * 4 + t) * 64 + lane) * 8];
#pragma unroll
    for (int i = 0; i < 4; i++)
#pragma unroll
      for (int j = 0; j < 4; j++)
        acc[i][j] =
            __builtin_amdgcn_mfma_f32_16x16x32_bf16(af[i], bfr[j], acc[i][j], 0, 0, 0);
  };

  stage(0, 0);
  stage(1, 1);
  int cur = 0, nxt = 2;
  for (int i = 0; i < 30; ++i) {
    WAITVM(4);
    sbar();
    stage(i + 2, nxt);
    compute(cur);
    cur = (cur == 2) ? 0 : cur + 1;
    nxt = (nxt == 2) ? 0 : nxt + 1;
  }
  WAITVM(4);
  sbar();
  compute(cur);
  cur = (cur == 2) ? 0 : cur + 1;
  WAITVM(0);
  sbar();
  compute(cur);

#pragma unroll
  for (int i = 0; i < 4; i++)
#pragma unroll
    for (int j = 0; j < 4; j++)
#pragma unroll
      for (int r = 0; r < 4; r++) {
        const int gr = rt * 128 + wr * 64 + i * 16 + lg * 4 + r;
        const int gc = ct * 128 + wc * 64 + j * 16 + l15;
        float v = acc[i][j][r];
        if (isKV) {
          v += bias[gc];
          const int b = gr >> 11, m = gr & 2047;
          const int kv = gc >> 10, hh = (gc >> 6) & 15, d = gc & 63;
          if (kv == 0)
            kws[((((size_t)b * 16 + hh) * 2048 + m) << 6) + d] = f2bf(v);
          else {
            // permuted V^T column so attn's in-register P-frag order matches
            const int mp = (m & ~31) | (((m >> 2) & 3) << 3) |
                           (((m >> 4) & 1) << 2) | (m & 3);
            vtws[(((size_t)b * 16 + hh) * 64 + d) * 2048 + mp] = f2bf(v);
          }
        } else {
          const int b = gr >> 10, n = gr & 1023, hh = gc >> 6, d = gc & 63;
          qws[((((size_t)b * 16 + hh) * 1024 + n) << 6) + d] = f2bf(v * SCL2E);
        }
      }
}

// ---------------------------------------------------------------------------
// attn_split (R17 structure + T5 setprio): swapped QK^T in-register P;
// NBUF=2 K/V full-phase counted-vmcnt cover; all 8 mask uint4 preloaded;
// fully unrolled. 512 blocks x 512 threads, split-K x2. LDS 64KB.
// ---------------------------------------------------------------------------
__global__ __launch_bounds__(512, 4)
void attn_split(const short* __restrict__ Qg, const short* __restrict__ Kg,
                const short* __restrict__ Vtg,
                const unsigned int* __restrict__ pm,
                float* __restrict__ opart, float* __restrict__ lpart) {
  __shared__ __align__(16) short ldsK[2][8192];
  __shared__ __align__(16) short ldsV[2][8192];
  const int tid = threadIdx.x;
  const int w = tid >> 6, lane = tid & 63;
  const int l15 = lane & 15, lg = lane >> 4;
  const int bx = blockIdx.x;
  const int bhid = bx & 31, qt = (bx >> 5) & 7, half = bx >> 8;
  const int b = bhid >> 4, h = bhid & 15;
  const int n0 = qt * 128, m_base = half * 1024;
  const size_t bh = (size_t)b * 16 + h;
  const short* Qb = Qg + (bh * 1024 + n0) * 64;
  const short* Kb = Kg + (bh << 17);
  const short* Vb = Vtg + (bh << 17);
  const unsigned int* pmw =
      pm + ((size_t)(b * 1024 + n0 + w * 16 + l15) << 6) + (m_base >> 5);

  uint4 mku[8];
#pragma unroll
  for (int c = 0; c < 8; c++) mku[c] = *(const uint4*)(pmw + c * 4);

  auto stageKV = [&](int c, int buf) {
    const int m0 = m_base + c * 128;
    short* dK = &ldsK[buf][0];
    short* dV = &ldsV[buf][0];
#pragma unroll
    for (int ii = 0; ii < 2; ii++) {
      const int f = w * 2 + ii;
      const int t = f >> 1, ks = f & 1;
      gld_lds16(Kb + (size_t)(m0 + t * 16 + l15) * 64 + ks * 32 + lg * 8,
                dK + f * 512);
      const int vt = f >> 2, vk = f & 3;
      gld_lds16(Vb + (size_t)(vt * 16 + l15) * 2048 + (m0 + vk * 32 + lg * 8),
                dV + f * 512);
    }
  };

#pragma unroll
  for (int ii = 0; ii < 2; ii++)
    gld_lds16(Qb + (size_t)(w * 16 + l15) * 64 + ii * 32 + lg * 8,
              &ldsV[1][(w * 2 + ii) * 512]);
  stageKV(0, 0);
  pipesync();
  short8 qf[2];
#pragma unroll
  for (int ks = 0; ks < 2; ks++)
    qf[ks] = *(const short8*)&ldsV[1][((w * 2 + ks) * 64 + lane) * 8];
  asm volatile("s_waitcnt lgkmcnt(0)" ::: "memory");
  sbar();

  short8 onesf;
#pragma unroll
  for (int i = 0; i < 8; i++) onesf[i] = (short)0x3F80;  // bf16 1.0

  f32x4 o[4], lacc;
#pragma unroll
  for (int ct = 0; ct < 4; ct++) o[ct] = (f32x4){0.f, 0.f, 0.f, 0.f};
  lacc = (f32x4){0.f, 0.f, 0.f, 0.f};
  const int sb = lg * 4;

  auto computeC = [&](uint4 mk, int buf) {
    const short* sK = &ldsK[buf][0];
    const short* sV = &ldsV[buf][0];
    int4v pw4[4];
#pragma unroll
    for (int h2 = 0; h2 < 2; h2++) {
      f32x4 s[4];
#pragma unroll
      for (int t2 = 0; t2 < 4; t2++) s[t2] = (f32x4){0.f, 0.f, 0.f, 0.f};
      __builtin_amdgcn_s_setprio(1);
#pragma unroll
      for (int t2 = 0; t2 < 4; t2++) {
        const int t = h2 * 4 + t2;
#pragma unroll
        for (int ks = 0; ks < 2; ks++) {
          const short8 kf = *(const short8*)&sK[((t * 2 + ks) * 64 + lane) * 8];
          s[t2] = __builtin_amdgcn_mfma_f32_16x16x32_bf16(kf, qf[ks], s[t2], 0, 0, 0);
        }
      }
      __builtin_amdgcn_s_setprio(0);
#pragma unroll
      for (int t2 = 0; t2 < 4; t2++) {
        const int t = h2 * 4 + t2;
        const unsigned int mw = ((t >> 1) == 0) ? mk.x
                              : ((t >> 1) == 1) ? mk.y
                              : ((t >> 1) == 2) ? mk.z : mk.w;
        float p[4];
#pragma unroll
        for (int r = 0; r < 4; r++) {
          const bool att = (mw >> (((t & 1) << 4) + sb + r)) & 1;
          p[r] = exp2f(att ? s[t2][r] : -1e30f);
        }
        pw4[t >> 1][(t & 1) * 2] = cvt_pk_bf16(p[0], p[1]);
        pw4[t >> 1][(t & 1) * 2 + 1] = cvt_pk_bf16(p[2], p[3]);
      }
    }
    __builtin_amdgcn_s_setprio(1);
#pragma unroll
    for (int ks2 = 0; ks2 < 4; ks2++) {
      const short8 pf = __builtin_bit_cast(short8, pw4[ks2]);
#pragma unroll
      for (int ct = 0; ct < 4; ct++) {
        const short8 vf = *(const short8*)&sV[((ct * 4 + ks2) * 64 + lane) * 8];
        o[ct] = __builtin_amdgcn_mfma_f32_16x16x32_bf16(pf, vf, o[ct], 0, 0, 0);
      }
      lacc = __builtin_amdgcn_mfma_f32_16x16x32_bf16(pf, onesf, lacc, 0, 0, 0);
    }
    __builtin_amdgcn_s_setprio(0);
  };

#pragma unroll
  for (int c = 0; c < 8; c++) {
    if (c + 1 < 8) {
      stageKV(c + 1, (c + 1) & 1);
      WAITVM(4);
    } else {
      WAITVM(0);
    }
    sbar();
    computeC(mku[c], c & 1);
    sbar();
  }

#pragma unroll
  for (int ct = 0; ct < 4; ct++)
#pragma unroll
    for (int r = 0; r < 4; r++) {
      const int n = n0 + w * 16 + lg * 4 + r;
      opart[((size_t)half << 21) + (((size_t)b * 1024 + n) << 10) + h * 64 +
            ct * 16 + l15] = o[ct][r];
    }
  if (l15 == 0) {
#pragma unroll
    for (int r = 0; r < 4; r++) {
      const int n = n0 + w * 16 + lg * 4 + r;
      lpart[((size_t)half << 15) + bh * 1024 + n] = lacc[r];
    }
  }
}

// ---------------------------------------------------------------------------
// combine (R21, output-linear): AO = (o0+o1)/(l0+l1), bf16, 64-tiled.
// ---------------------------------------------------------------------------
__global__ __launch_bounds__(256) void combine(
    const float* __restrict__ opart, const float* __restrict__ lpart,
    short* __restrict__ aoT) {
  const int gid = blockIdx.x * 256 + threadIdx.x;  // [0, 524288)
  const int T = gid * 4;
  const int j = T & 4, r15 = (T >> 3) & 15, q = (T >> 7) & 3;
  const int f = (T >> 9) & 3, kc = (T >> 11) & 31, rt = T >> 16;
  const int row = rt * 64 + f * 16 + r15;
  const int col = kc * 32 + q * 8 + j;
  const int b = row >> 10, n = row & 1023, h = col >> 6;
  const size_t src = (((size_t)row) << 10) + col;
  const float4 o1 = *(const float4*)(opart + src);
  const float4 o2 = *(const float4*)(opart + (1u << 21) + src);
  const float l1 = lpart[(size_t)(b * 16 + h) * 1024 + n];
  const float l2 = lpart[(1u << 15) + (size_t)(b * 16 + h) * 1024 + n];
  const float inv = 1.f / fmaxf(l1 + l2, 1e-30f);
  short4v o;
  o[0] = f2bf((o1.x + o2.x) * inv); o[1] = f2bf((o1.y + o2.y) * inv);
  o[2] = f2bf((o1.z + o2.z) * inv); o[3] = f2bf((o1.w + o2.w) * inv);
  *(short4v*)(aoT + T) = o;
}

// ---------------------------------------------------------------------------
// o_gemm (R17, unchanged): 64x64 tiles, BK=64 (16 phases x 8 MFMA),
// 512 blocks, NBUF=3 (48KB LDS, 3 blocks/CU), counted vmcnt(4), XCD swizzle.
// ---------------------------------------------------------------------------
__global__ __launch_bounds__(256, 3)
void o_gemm(const short* __restrict__ aoT, const short* __restrict__ wobT,
            float* __restrict__ Of) {
  __shared__ __align__(16) short ldsA[3][4096];
  __shared__ __align__(16) short ldsB[3][4096];
  const int tid = threadIdx.x;
  const int w = tid >> 6, lane = tid & 63;
  const int l15 = lane & 15, lg = lane >> 4;
  const int bx0 = blockIdx.x;
  const int bx = (bx0 & 7) * 64 + (bx0 >> 3);
  const int rt = bx >> 4, ct = bx & 15;

  f32x4 acc[4];
#pragma unroll
  for (int j = 0; j < 4; j++) acc[j] = (f32x4){0.f, 0.f, 0.f, 0.f};

  const short* ga = aoT + (size_t)rt * 65536 + w * 512 + lane * 8;
  const short* gb = wobT + (size_t)ct * 65536 + w * 512 + lane * 8;

  auto stage = [&](int t, int buf) {
    const size_t koff = (size_t)t * 4096;
    gld_lds16(ga + koff, &ldsA[buf][0] + w * 512);
    gld_lds16(ga + koff + 2048, &ldsA[buf][0] + 2048 + w * 512);
    gld_lds16(gb + koff, &ldsB[buf][0] + w * 512);
    gld_lds16(gb + koff + 2048, &ldsB[buf][0] + 2048 + w * 512);
  };
  auto compute = [&](int buf) {
    const short* sA = &ldsA[buf][0];
    const short* sB = &ldsB[buf][0];
    const short8 af0 = *(const short8*)&sA[(w * 64 + lane) * 8];
    const short8 af1 = *(const short8*)&sA[2048 + (w * 64 + lane) * 8];
#pragma unroll
    for (int j = 0; j < 4; j++) {
      const short8 bf0 = *(const short8*)&sB[(j * 64 + lane) * 8];
      const short8 bf1 = *(const short8*)&sB[2048 + (j * 64 + lane) * 8];
      acc[j] = __builtin_amdgcn_mfma_f32_16x16x32_bf16(af0, bf0, acc[j], 0, 0, 0);
      acc[j] = __builtin_amdgcn_mfma_f32_16x16x32_bf16(af1, bf1, acc[j], 0, 0, 0);
    }
  };

  stage(0, 0);
  stage(1, 1);
#pragma unroll
  for (int i = 0; i < 14; ++i) {
    WAITVM(4);
    sbar();
    stage(i + 2, (i + 2) % 3);
    compute(i % 3);
  }
  WAITVM(4);
  sbar();
  compute(14 % 3);
  WAITVM(0);
  sbar();
  compute(15 % 3);

#pragma unroll
  for (int j = 0; j < 4; j++)
#pragma unroll
    for (int r = 0; r < 4; r++) {
      const int gr = rt * 64 + w * 16 + lg * 4 + r;
      const int gc = ct * 64 + j * 16 + l15;
      Of[(size_t)gr * 1024 + gc] = acc[j][r];
    }
}

extern "C" void kernel_launch(void* const* d_in, const int* in_sizes, int n_in,
                              void* d_out, int out_size, void* d_ws, size_t ws_size,
                              hipStream_t stream) {
  const float* x   = (const float*)d_in[0];   // fp32 (2,1024,1024)
  const float* ctx = (const float*)d_in[1];   // fp32 (2,2048,1024)
  const unsigned char* mask = (const unsigned char*)d_in[2];  // (2,1024,2048)
  const float* Wq  = (const float*)d_in[3];
  const float* Wkv = (const float*)d_in[4];
  const float* bkv = (const float*)d_in[5];
  const float* Wo  = (const float*)d_in[6];
  float* out = (float*)d_out;                 // FP32 (2,1024,1024)

  char* wsb = (char*)d_ws;
  short* qws  = (short*)(wsb);                        // bf16 Q*scl  4MB @0
  short* kws  = (short*)(wsb + (4u << 20));           // bf16 K      8MB @4M
  short* vtws = (short*)(wsb + (12u << 20));          // bf16 V^T    8MB @12M
  short* wqb  = (short*)(wsb + (20u << 20));          // bf16 Wq(T)  2MB @20M
  short* wkvb = (short*)(wsb + (22u << 20));          // bf16 Wkv(T) 4MB @22M
  short* wob  = (short*)(wsb + (26u << 20));          // bf16 Wo(T)  2MB @26M
  unsigned long long* pmws = (unsigned long long*)(wsb + (28u << 20));  // .5MB
  float* opart = (float*)(wsb + (29u << 20));         // fp32 2x8MB  16MB @29M
  float* lpart = (float*)(wsb + (45u << 20));         // fp32 .25MB  @45M
  short* xb   = (short*)(wsb + (29u << 20));          // bf16 x(T)   4MB @29M
  short* ctxb = (short*)(wsb + (33u << 20));          // bf16 ctx(T) 8MB @33M
  short* ao = (short*)(wsb + (20u << 20));  // bf16 AO(T) 4MB (reuses wqb/wkvb)

  prep<<<2048, 256, 0, stream>>>(mask, pmws, Wq, Wkv, Wo, x, ctx,
                                 wqb, wkvb, wob, xb, ctxb);
  qkv_gemm<<<640, 256, 0, stream>>>(xb, ctxb, wqb, wkvb, bkv, qws, kws, vtws);
  attn_split<<<512, 512, 0, stream>>>(qws, kws, vtws, (const unsigned int*)pmws,
                                      opart, lpart);
  combine<<<2048, 256, 0, stream>>>(opart, lpart, ao);
  o_gemm<<<512, 256, 0, stream>>>(ao, wob, out);
}